// Round 7
// baseline (30.499 us; speedup 1.0000x reference)
//
#include <hip/hip_runtime.h>
#include <math.h>

// Spline geometry (uniform knots): lo = -18, dist = 36/29, 1/dist = 29/36
#define SP_INV_DIST (29.0f / 36.0f)
#define SP_U_OFFS   (17.5f)              // 3 - lo/dist
// -0.5*log(2*pi) + log(1/dist) : deriv's 1/dist folded in additively
#define C_CONST (-1.13516164467f)
#define LN2 (0.69314718056f)

typedef float f32x4 __attribute__((ext_vector_type(4)));

// ---------------------------------------------------------------------------
// Per-element: clamp -> span -> TWO LDS float4 reads off ONE address
// (value cubic at tab[s], deriv quadratic at tab[s+32] -> offset:512 imm)
// -> Horner -> logprob.
// ---------------------------------------------------------------------------
__device__ __forceinline__ float eval_one(float xin, const float4* __restrict__ tab) {
    float x = __builtin_amdgcn_fmed3f(xin, -15.0f, 15.0f);   // clamp, 1 inst
    float u = fmaf(x, SP_INV_DIST, SP_U_OFFS);               // in [5.41, 29.59]
    int   s = (int)u;
#if __has_builtin(__builtin_amdgcn_fractf)
    float f = __builtin_amdgcn_fractf(u);
#else
    float f = u - (float)s;
#endif
    float4 a = tab[s];
    float4 q = tab[s + 32];                                  // same addr +512B
    float val = fmaf(fmaf(fmaf(a.w, f, a.z), f, a.y), f, a.x);
    float der = fmaf(fmaf(q.z, f, q.y), f, q.x);             // d(val)/df  (>0)
    float l2  = __log2f(der);                                // raw v_log_f32
    return fmaf(LN2, l2, fmaf(-0.5f * val, val, C_CONST));
}

__device__ __forceinline__ f32x4 eval4(f32x4 v, const float4* __restrict__ tab) {
    f32x4 r;
    r.x = eval_one(v.x, tab); r.y = eval_one(v.y, tab);
    r.z = eval_one(v.z, tab); r.w = eval_one(v.w, tab);
    return r;
}

// ---------------------------------------------------------------------------
// Persistent streamer, prefetch DEPTH 2: stages A (oldest) and B in flight;
// iteration k issues its loads before retiring iteration k-2. ~64 B/lane
// continuously outstanding. 2048 blocks x 256 thr, 8 blk/CU residency.
// ---------------------------------------------------------------------------
__global__ __launch_bounds__(256) void TM_73727408603569_kernel(
        const float* __restrict__ y, const float* __restrict__ params,
        float* __restrict__ out, int n4, int tail_base, int tail) {
    __shared__ float4 tab[64];          // [0..31] value poly, [32..63] deriv poly
    int t = threadIdx.x;

    if (t < 64) {                       // wave 0 only: build tables
        bool lane_p = (t >= 1 && t < 32);
        float p  = lane_p ? params[t] : 0.0f;
        float sp = lane_p ? ((p > 0.0f) ? (p + log1pf(expf(-p)))
                                        : log1pf(expf(p)))
                          : 0.0f;
        #pragma unroll
        for (int d = 1; d < 32; d <<= 1) {      // inclusive scan across lanes
            float o = __shfl_up(sp, d, 64);
            if (t >= d) sp += o;
        }
        float c  = params[0] + sp;              // monotonic coef t
        float d0 = __shfl_up(c, 3, 64);
        float d1 = __shfl_up(c, 2, 64);
        float d2 = __shfl_up(c, 1, 64);
        float d3 = c;
        if (t < 32) {
            float4 vp = make_float4(0.f, 0.f, 0.f, 0.f);
            float4 dp = make_float4(0.f, 0.f, 0.f, 0.f);
            if (t >= 3) {                        // B-spline -> power basis in f
                const float SIXTH = 1.0f / 6.0f;
                vp.x = (d0 + 4.0f * d1 + d2) * SIXTH;
                vp.y = (d2 - d0) * 0.5f;
                vp.z = (d0 - 2.0f * d1 + d2) * 0.5f;
                vp.w = (d3 - d0 + 3.0f * (d1 - d2)) * SIXTH;
                dp.x = vp.y;                     // a1
                dp.y = vp.z + vp.z;              // 2*a2
                dp.z = 3.0f * vp.w;              // 3*a3
            }
            tab[t]      = vp;
            tab[32 + t] = dp;
        }
    }
    __syncthreads();

    const f32x4* y4 = reinterpret_cast<const f32x4*>(y);
    f32x4*       o4 = reinterpret_cast<f32x4*>(out);

    const int S  = gridDim.x << 9;              // stride: blocks * 512 float4
    const int bb = blockIdx.x << 9;
    int niter = (n4 > bb) ? ((n4 - 1 - bb) / S + 1) : 0;   // block-uniform

    int  iA = bb + t, iB = iA + S;
    bool A0p = false, A1p = false, B0p = false, B1p = false;
    f32x4 A0v, A1v, B0v, B1v;
    if (niter >= 1) {
        A0p = iA < n4; A1p = (iA + 256) < n4;
        if (A0p) A0v = y4[iA];
        if (A1p) A1v = y4[iA + 256];
    }
    if (niter >= 2) {
        B0p = iB < n4; B1p = (iB + 256) < n4;
        if (B0p) B0v = y4[iB];
        if (B1p) B1v = y4[iB + 256];
    }
    for (int k = 2; k < niter; ++k) {
        int  iC  = iA + 2 * S;
        bool C0p = iC < n4, C1p = (iC + 256) < n4;
        f32x4 C0v, C1v;
        if (C0p) C0v = y4[iC];                  // issue iter-k loads first
        if (C1p) C1v = y4[iC + 256];
        if (A0p) o4[iA]       = eval4(A0v, tab);   // retire iter k-2
        if (A1p) o4[iA + 256] = eval4(A1v, tab);
        iA = iB; A0p = B0p; A1p = B1p; A0v = B0v; A1v = B1v;
        iB = iC; B0p = C0p; B1p = C1p; B0v = C0v; B1v = C1v;
    }
    if (niter >= 1) {
        if (A0p) o4[iA]       = eval4(A0v, tab);
        if (A1p) o4[iA + 256] = eval4(A1v, tab);
    }
    if (niter >= 2) {
        if (B0p) o4[iB]       = eval4(B0v, tab);
        if (B1p) o4[iB + 256] = eval4(B1v, tab);
    }

    // scalar tail (n not multiple of 4)
    if (blockIdx.x == 0 && t < tail) {
        int idx = tail_base + t;
        out[idx] = eval_one(y[idx], tab);
    }
}

extern "C" void kernel_launch(void* const* d_in, const int* in_sizes, int n_in,
                              void* d_out, int out_size, void* d_ws, size_t ws_size,
                              hipStream_t stream) {
    const float* params = (const float*)d_in[0];
    const float* y      = (const float*)d_in[1];
    float*       out    = (float*)d_out;
    int n    = in_sizes[1];
    int n4   = n >> 2;
    int tail = n & 3;

    int blocks = (n4 + 511) / 512;
    if (blocks > 2048) blocks = 2048;
    if (blocks < 1) blocks = 1;
    TM_73727408603569_kernel<<<blocks, 256, 0, stream>>>(y, params, out, n4,
                                                         n4 << 2, tail);
}

// Round 8
// 29.766 us; speedup vs baseline: 1.0246x; 1.0246x over previous
//
#include <hip/hip_runtime.h>
#include <math.h>

// Spline geometry (uniform knots): lo = -18, dist = 36/29, 1/dist = 29/36
#define SP_INV_DIST (29.0f / 36.0f)
#define SP_U_OFFS   (17.5f)              // 3 - lo/dist
// -0.5*log(2*pi) + log(1/dist) : deriv's 1/dist folded in additively
#define C_CONST (-1.13516164467f)
#define LN2 (0.69314718056f)

typedef float f32x4 __attribute__((ext_vector_type(4)));

// ---------------------------------------------------------------------------
// Per-element: clamp -> span -> TWO LDS float4 reads off ONE address
// (value cubic at tab[s], deriv quadratic at tab[s+32] -> offset:512 imm)
// -> Horner -> logprob.
// ---------------------------------------------------------------------------
__device__ __forceinline__ float eval_one(float xin, const float4* __restrict__ tab) {
    float x = __builtin_amdgcn_fmed3f(xin, -15.0f, 15.0f);   // clamp, 1 inst
    float u = fmaf(x, SP_INV_DIST, SP_U_OFFS);               // in [5.41, 29.59]
    int   s = (int)u;
#if __has_builtin(__builtin_amdgcn_fractf)
    float f = __builtin_amdgcn_fractf(u);
#else
    float f = u - (float)s;
#endif
    float4 a = tab[s];
    float4 q = tab[s + 32];                                  // same addr +512B
    float val = fmaf(fmaf(fmaf(a.w, f, a.z), f, a.y), f, a.x);
    float der = fmaf(fmaf(q.z, f, q.y), f, q.x);             // d(val)/df  (>0)
    float l2  = __log2f(der);                                // raw v_log_f32
    return fmaf(LN2, l2, fmaf(-0.5f * val, val, C_CONST));
}

__device__ __forceinline__ f32x4 eval4(f32x4 v, const float4* __restrict__ tab) {
    f32x4 r;
    r.x = eval_one(v.x, tab); r.y = eval_one(v.y, tab);
    r.z = eval_one(v.z, tab); r.w = eval_one(v.w, tab);
    return r;
}

// ---------------------------------------------------------------------------
// Persistent software-pipelined streamer (depth 1, width 2 — best measured).
// 2048 blocks x 256 thr (8 blk/CU). Each iteration issues the NEXT pair of
// float4 loads before evaluating/storing the CURRENT pair.
// ---------------------------------------------------------------------------
__global__ __launch_bounds__(256) void TM_73727408603569_kernel(
        const float* __restrict__ y, const float* __restrict__ params,
        float* __restrict__ out, int n4, int tail_base, int tail) {
    __shared__ float4 tab[64];          // [0..31] value poly, [32..63] deriv poly
    int t = threadIdx.x;

    if (t < 64) {                       // wave 0 only: build tables
        bool lane_p = (t >= 1 && t < 32);
        float p  = lane_p ? params[t] : 0.0f;
        float sp = lane_p ? ((p > 0.0f) ? (p + log1pf(expf(-p)))
                                        : log1pf(expf(p)))
                          : 0.0f;
        #pragma unroll
        for (int d = 1; d < 32; d <<= 1) {      // inclusive scan across lanes
            float o = __shfl_up(sp, d, 64);
            if (t >= d) sp += o;
        }
        float c  = params[0] + sp;              // monotonic coef t
        float d0 = __shfl_up(c, 3, 64);
        float d1 = __shfl_up(c, 2, 64);
        float d2 = __shfl_up(c, 1, 64);
        float d3 = c;
        if (t < 32) {
            float4 vp = make_float4(0.f, 0.f, 0.f, 0.f);
            float4 dp = make_float4(0.f, 0.f, 0.f, 0.f);
            if (t >= 3) {                        // B-spline -> power basis in f
                const float SIXTH = 1.0f / 6.0f;
                vp.x = (d0 + 4.0f * d1 + d2) * SIXTH;
                vp.y = (d2 - d0) * 0.5f;
                vp.z = (d0 - 2.0f * d1 + d2) * 0.5f;
                vp.w = (d3 - d0 + 3.0f * (d1 - d2)) * SIXTH;
                dp.x = vp.y;                     // a1
                dp.y = vp.z + vp.z;              // 2*a2
                dp.z = 3.0f * vp.w;              // 3*a3
            }
            tab[t]      = vp;
            tab[32 + t] = dp;
        }
    }
    __syncthreads();

    const f32x4* y4 = reinterpret_cast<const f32x4*>(y);
    f32x4*       o4 = reinterpret_cast<f32x4*>(out);

    const int S  = gridDim.x << 9;              // stride: blocks * 512 float4
    const int bb = blockIdx.x << 9;             // this block's first slot
    int niter = (n4 > bb) ? ((n4 - 1 - bb) / S + 1) : 0;   // block-uniform

    int  i0 = bb + t, i1 = i0 + 256;
    bool q0 = i0 < n4, q1 = i1 < n4;
    f32x4 c0, c1;
    if (niter > 0) {
        if (q0) c0 = y4[i0];
        if (q1) c1 = y4[i1];
        for (int k = 1; k < niter; ++k) {
            int  j0 = i0 + S, j1 = i1 + S;
            bool r0 = j0 < n4, r1 = j1 < n4;
            f32x4 nx0, nx1;
            if (r0) nx0 = y4[j0];               // prefetch next sweep
            if (r1) nx1 = y4[j1];
            if (q0) o4[i0] = eval4(c0, tab);    // finish current sweep
            if (q1) o4[i1] = eval4(c1, tab);
            i0 = j0; i1 = j1; q0 = r0; q1 = r1; c0 = nx0; c1 = nx1;
        }
        if (q0) o4[i0] = eval4(c0, tab);
        if (q1) o4[i1] = eval4(c1, tab);
    }

    // scalar tail (n not multiple of 4)
    if (blockIdx.x == 0 && t < tail) {
        int idx = tail_base + t;
        out[idx] = eval_one(y[idx], tab);
    }
}

extern "C" void kernel_launch(void* const* d_in, const int* in_sizes, int n_in,
                              void* d_out, int out_size, void* d_ws, size_t ws_size,
                              hipStream_t stream) {
    const float* params = (const float*)d_in[0];
    const float* y      = (const float*)d_in[1];
    float*       out    = (float*)d_out;
    int n    = in_sizes[1];
    int n4   = n >> 2;
    int tail = n & 3;

    int blocks = (n4 + 511) / 512;
    if (blocks > 2048) blocks = 2048;
    if (blocks < 1) blocks = 1;
    TM_73727408603569_kernel<<<blocks, 256, 0, stream>>>(y, params, out, n4,
                                                         n4 << 2, tail);
}